// Round 12
// baseline (212.416 us; speedup 1.0000x reference)
//
#include <hip/hip_runtime.h>
#include <hip/hip_bf16.h>
#include <math.h>

#define B_    8
#define S_    8192
#define DIN_  512
#define DH_   512
#define HN_   4
#define HD_   128
#define CHUNK_ 16
#define NC_   (S_/CHUNK_)
#define NTOK  (B_*S_)

typedef __bf16 bf16x8 __attribute__((ext_vector_type(8)));
typedef float  f32x4  __attribute__((ext_vector_type(4)));

__device__ __forceinline__ float sigmoidf_(float z) { return 1.0f / (1.0f + expf(-z)); }

__device__ __forceinline__ unsigned short f2bf(float f) {
    union { float f; unsigned u; } v; v.f = f;
    unsigned u = v.u;
    u += 0x7fffu + ((u >> 16) & 1u);   // RNE
    return (unsigned short)(u >> 16);
}
__device__ __forceinline__ float bf2f(unsigned short s) {
    union { unsigned u; float f; } c; c.u = ((unsigned)s) << 16; return c.f;
}
// compiler casts -> v_cvt_pk_bf16_f32 (RNE, same numerics as manual f2bf)
__device__ __forceinline__ unsigned long long pack4bf(float4 a) {
    union { __bf16 h[4]; unsigned long long u; } c;
    c.h[0] = (__bf16)a.x; c.h[1] = (__bf16)a.y;
    c.h[2] = (__bf16)a.z; c.h[3] = (__bf16)a.w;
    return c.u;
}
__device__ __forceinline__ void gload_lds16(const void* g, void* lds) {
    __builtin_amdgcn_global_load_lds(
        (const __attribute__((address_space(1))) unsigned int*)g,
        (__attribute__((address_space(3))) unsigned int*)lds, 16, 0, 0);
}

// A-tile LDS byte offset within an 8KB subtile, XOR-swizzled (both sides)
#define AOFF(og, r) ((((og) << 11) + ((r) << 4)) ^ ((og) << 5))
// Linear subtile byte offset (global_load_lds dest / pre-packed operands)
#define BOFF(og, c) (((og) << 11) + ((c) << 4))

// XCD-grouping decode: the 4 ct-blocks of an mt land on the SAME XCD,
// temporally adjacent (default dispatch: xcd = blockIdx % 8).
#define XCD_DECODE(mt, ct)                        \
    const int _bid = blockIdx.x;                  \
    const int _j = _bid >> 3;                     \
    const int mt = ((_j >> 2) << 3) + (_bid & 7); \
    const int ct = _j & 3;

// ---------------------------------------------------------------------------
// k0: W (f32 [512][512], row=outcol) -> bf16 tiled layout (8KB tiles):
//   half-index = (((ct*16 + kt)*4 + og) << 10) + (c << 3) + kk
// ---------------------------------------------------------------------------
__global__ __launch_bounds__(256) void k0_convert(
    const float* __restrict__ Win, const float* __restrict__ Wout,
    unsigned short* __restrict__ WreA, unsigned short* __restrict__ WreB)
{
    int idx = blockIdx.x * 256 + threadIdx.x;
    if (idx < 262144) {
        int c_g = idx >> 9, k = idx & 511;
        int dst = ((((c_g >> 7) * 16 + (k >> 5)) * 4 + ((k >> 3) & 3)) << 10)
                + ((c_g & 127) << 3) + (k & 7);
        WreA[dst] = f2bf(Win[idx]);
        WreB[dst] = f2bf(Wout[idx]);
    }
}

// ---------------------------------------------------------------------------
// gemm1: xpb = bf16(x @ Win^T). 128x128 tile, 4 waves 2x2, TWO 32-k subtiles
// per barrier-pair (8 barrier-pairs instead of 16), 32 KB LDS.
// __launch_bounds__(256,4): clamp to 128 unified regs -> 4 waves/SIMD.
// ---------------------------------------------------------------------------
__global__ __launch_bounds__(256, 4) void gemm1(
    const float* __restrict__ x, const unsigned short* __restrict__ Wre,
    unsigned short* __restrict__ xpb)
{
    __shared__ alignas(16) unsigned short Bl[8192];  // 16 KB: 2 subtiles
    __shared__ alignas(16) unsigned short Al[8192];  // 16 KB: 2 subtiles
    char* Blc = (char*)Bl; char* Alc = (char*)Al;
    const int tid = threadIdx.x;
    const int l = tid & 63, wid = tid >> 6;
    const int og = l >> 4, lr = l & 15;
    const int wr = wid >> 1, wc2 = wid & 1;
    XCD_DECODE(mt, ct)
    const long t0 = (long)mt * 128;
    const int c0 = ct << 7;
    const int r0 = tid >> 2, ogk = tid & 3;

    f32x4 acc[4][4];
    #pragma unroll
    for (int m = 0; m < 4; ++m)
        #pragma unroll
        for (int n = 0; n < 4; ++n) acc[m][n] = (f32x4)(0.f);

    for (int kt2 = 0; kt2 < 8; ++kt2) {
        __syncthreads();
        #pragma unroll
        for (int s = 0; s < 2; ++s) {
            const int kt = (kt2 << 1) + s;
            const char* gB = (const char*)Wre + ((long)(ct * 16 + kt) << 13);
            char* BlS = Blc + (s << 13);
            gload_lds16(gB + (wid << 10) + (l << 4),        BlS + (wid << 10));
            gload_lds16(gB + 4096 + (wid << 10) + (l << 4), BlS + 4096 + (wid << 10));
            const int kb = kt << 5;
            const float* xr0 = &x[(t0 + r0) * 512 + kb + (ogk << 3)];
            const float* xr1 = &x[(t0 + r0 + 64) * 512 + kb + (ogk << 3)];
            float4 a0 = *(const float4*)xr0, a1 = *(const float4*)(xr0 + 4);
            float4 b0 = *(const float4*)xr1, b1 = *(const float4*)(xr1 + 4);
            ulonglong2 w0, w1;
            w0.x = pack4bf(a0); w0.y = pack4bf(a1);
            w1.x = pack4bf(b0); w1.y = pack4bf(b1);
            char* AlS = Alc + (s << 13);
            *(ulonglong2*)(AlS + AOFF(ogk, r0))      = w0;
            *(ulonglong2*)(AlS + AOFF(ogk, r0 + 64)) = w1;
        }
        __syncthreads();

        #pragma unroll
        for (int s = 0; s < 2; ++s) {
            const char* AlS = Alc + (s << 13);
            const char* BlS = Blc + (s << 13);
            bf16x8 afr[4], bfr[4];
            #pragma unroll
            for (int m = 0; m < 4; ++m)
                afr[m] = *(const bf16x8*)(AlS + AOFF(og, (wr << 6) + (m << 4) + lr));
            #pragma unroll
            for (int n = 0; n < 4; ++n)
                bfr[n] = *(const bf16x8*)(BlS + BOFF(og, (wc2 << 6) + (n << 4) + lr));
            #pragma unroll
            for (int m = 0; m < 4; ++m)
                #pragma unroll
                for (int n = 0; n < 4; ++n)
                    acc[m][n] = __builtin_amdgcn_mfma_f32_16x16x32_bf16(afr[m], bfr[n], acc[m][n], 0, 0, 0);
        }
    }

    #pragma unroll
    for (int m = 0; m < 4; ++m) {
        const long rb = t0 + (wr << 6) + (m << 4) + (og << 2);
        #pragma unroll
        for (int n = 0; n < 4; ++n) {
            const int col = c0 + (wc2 << 6) + (n << 4) + lr;
            #pragma unroll
            for (int j = 0; j < 4; ++j)
                xpb[(rb + j) * 512 + col] = f2bf(acc[m][n][j]);
        }
    }
}

// ---------------------------------------------------------------------------
// k_lnA: block = 1 chunk (16 tokens), token-parallel (16 lanes/token).
// Reads xpb (bf16). LN -> gates -> bn -> cumprod p -> clamped cumsum B0.
// Writes p_buf, B15 (f32), and B0 packed bf16 in gemm2's tiled A layout.
// ---------------------------------------------------------------------------
__global__ __launch_bounds__(256) void k_lnA(
    const unsigned short* __restrict__ xpb,
    const float* __restrict__ gamma, const float* __restrict__ beta,
    const float* __restrict__ Wg, const float* __restrict__ bg,
    const float* __restrict__ eig_raw,
    unsigned short* __restrict__ A2, float* __restrict__ B15,
    float* __restrict__ p_buf)
{
    __shared__ float bnS[16][512];   // 32 KB
    __shared__ float WgL[8][512];    // 16 KB
    __shared__ float qS[16][4];
    __shared__ float rqS[16][4];
    __shared__ float aS[16][4];

    const int tid = threadIdx.x;
    const int l = tid & 63, w = tid >> 6;
    const int lg = l >> 4;
    const int li = l & 15;
    const int r  = (w << 2) + lg;
    const long t0 = (long)blockIdx.x * 16;
    const long tok = t0 + r;

    float4 v[8];
    #pragma unroll
    for (int jj = 0; jj < 8; ++jj) {
        const ushort4 u = *(const ushort4*)&xpb[tok * 512 + (jj << 6) + (li << 2)];
        v[jj] = make_float4(bf2f(u.x), bf2f(u.y), bf2f(u.z), bf2f(u.w));
    }

    #pragma unroll
    for (int i = 0; i < 4; ++i)
        ((float4*)WgL)[tid + 256 * i] = ((const float4*)Wg)[tid + 256 * i];
    __syncthreads();

    float s1 = 0.f, s2 = 0.f;
    #pragma unroll
    for (int jj = 0; jj < 8; ++jj) {
        s1 += v[jj].x + v[jj].y + v[jj].z + v[jj].w;
        s2 += v[jj].x*v[jj].x + v[jj].y*v[jj].y + v[jj].z*v[jj].z + v[jj].w*v[jj].w;
    }
    #pragma unroll
    for (int o = 1; o < 16; o <<= 1) { s1 += __shfl_xor(s1, o, 64); s2 += __shfl_xor(s2, o, 64); }
    const float mean = s1 * (1.f/512.f);
    const float var  = s2 * (1.f/512.f) - mean*mean;
    const float rstd = 1.0f / sqrtf(var + 1e-5f);

    #pragma unroll
    for (int jj = 0; jj < 8; ++jj) {
        const float4 g = *(const float4*)&gamma[(jj << 6) + (li << 2)];
        const float4 b = *(const float4*)&beta[(jj << 6) + (li << 2)];
        v[jj].x = (v[jj].x - mean)*rstd*g.x + b.x;
        v[jj].y = (v[jj].y - mean)*rstd*g.y + b.y;
        v[jj].z = (v[jj].z - mean)*rstd*g.z + b.z;
        v[jj].w = (v[jj].w - mean)*rstd*g.w + b.w;
    }

    float gt[8];
    #pragma unroll
    for (int g = 0; g < 8; ++g) {
        float p = 0.f;
        #pragma unroll
        for (int jj = 0; jj < 8; ++jj) {
            const float4 wv = *(const float4*)&WgL[g][(jj << 6) + (li << 2)];
            p = fmaf(v[jj].x, wv.x, p); p = fmaf(v[jj].y, wv.y, p);
            p = fmaf(v[jj].z, wv.z, p); p = fmaf(v[jj].w, wv.w, p);
        }
        #pragma unroll
        for (int o = 1; o < 16; o <<= 1) p += __shfl_xor(p, o, 64);
        gt[g] = p + bg[g];
    }

    const float bt[4] = {sigmoidf_(gt[4]), sigmoidf_(gt[5]), sigmoidf_(gt[6]), sigmoidf_(gt[7])};
    #pragma unroll
    for (int jj = 0; jj < 8; ++jj) {
        const float b = bt[jj >> 1];
        *(float4*)&bnS[r][(jj << 6) + (li << 2)] =
            make_float4(b*v[jj].x, b*v[jj].y, b*v[jj].z, b*v[jj].w);
    }
    if (li < 4) aS[r][li] = tanhf(eig_raw[li]) * sigmoidf_(gt[li]);
    __syncthreads();

    if (tid < 4) {
        const int n = tid;
        float p = 1.f;
        #pragma unroll
        for (int t = 0; t < 16; ++t) {
            p *= aS[t][n];
            p_buf[(t0 + t) * 4 + n] = p;
            const float q = fmaxf(p, 1e-6f);
            qS[t][n] = q;
            rqS[t][n] = 1.0f / q;
        }
    }
    __syncthreads();

    #pragma unroll
    for (int cc = 0; cc < 2; ++cc) {
        const int c = tid + (cc << 8);
        const int n = c >> 7;
        float s = 0.f;
        #pragma unroll
        for (int t = 0; t < 16; ++t) {
            s = fmaf(bnS[t][c], rqS[t][n], s);
            const float vv = qS[t][n] * s;
            bnS[t][c] = vv;
            if (t == 15) B15[blockIdx.x * 512 + c] = vv;
        }
    }
    __syncthreads();

    const long mtb = t0 >> 7;
    #pragma unroll
    for (int i = 0; i < 4; ++i) {
        const int slot = (i << 8) + tid;
        const int t = slot >> 6, oct = slot & 63;
        const float4 va = *(const float4*)&bnS[t][oct << 3];
        const float4 vb = *(const float4*)&bnS[t][(oct << 3) + 4];
        const int rr = (int)((t0 + t) & 127);
        const long idx = (((mtb * 16 + (oct >> 2)) * 4 + (oct & 3)) << 10) + (rr << 3);
        ulonglong2 wv; wv.x = pack4bf(va); wv.y = pack4bf(vb);
        *(ulonglong2*)&A2[idx] = wv;
    }
}

// ---------------------------------------------------------------------------
// Two-level parallel scan over 512 chunk carries (groups of 16).
// ---------------------------------------------------------------------------
__global__ __launch_bounds__(256) void k3a_compose(
    const float* __restrict__ p_buf, const float* __restrict__ B15,
    float* __restrict__ Pg, float* __restrict__ Qg)
{
    const int gid = blockIdx.x * 256 + threadIdx.x;   // 0..131071
    const int c = gid & 511, g = (gid >> 9) & 31, b = gid >> 14;
    const int n = c >> 7;
    float P = 1.f, Q = 0.f;
    #pragma unroll
    for (int j = 0; j < 16; ++j) {
        const int ch = (g << 4) + j;
        const long gc = (long)b * NC_ + ch;
        const long sE = (long)b * S_ + (long)ch * CHUNK_ + (CHUNK_ - 1);
        const float p15 = p_buf[sE * HN_ + n];
        const float b15 = B15[gc * 512 + c];
        P *= p15;
        Q = fmaf(p15, Q, b15);
    }
    Pg[(long)gid] = P;
    Qg[(long)gid] = Q;
}

__global__ __launch_bounds__(256) void k3b_scan(
    const float* __restrict__ Pg, const float* __restrict__ Qg,
    const float* __restrict__ h_in, float* __restrict__ h0g,
    float* __restrict__ h_last)
{
    const int tid = blockIdx.x * blockDim.x + threadIdx.x; // 0..4095
    const int b = tid >> 9, c = tid & 511;
    float h = h_in[b * DH_ + c];
    for (int g = 0; g < 32; ++g) {
        const long i = ((long)(b * 32 + g)) * 512 + c;
        h0g[i] = h;
        h = fmaf(Pg[i], h, Qg[i]);
    }
    h_last[b * DH_ + c] = h;
}

__global__ __launch_bounds__(256) void k3c_expand(
    const float* __restrict__ p_buf, const float* __restrict__ B15,
    const float* __restrict__ h0g, float* __restrict__ h0_buf)
{
    const int gid = blockIdx.x * 256 + threadIdx.x;   // 0..131071
    const int c = gid & 511, g = (gid >> 9) & 31, b = gid >> 14;
    const int n = c >> 7;
    float h = h0g[(long)gid];
    #pragma unroll
    for (int j = 0; j < 16; ++j) {
        const int ch = (g << 4) + j;
        const long gc = (long)b * NC_ + ch;
        h0_buf[gc * 512 + c] = h;
        const long sE = (long)b * S_ + (long)ch * CHUNK_ + (CHUNK_ - 1);
        h = fmaf(p_buf[sE * HN_ + n], h, B15[gc * 512 + c]);
    }
}

// ---------------------------------------------------------------------------
// kG: G[hn][gc][col] = sum_{k in hn slice} h0[gc][k] * Wout[col][k].
// Two subtiles per barrier-pair (2 pairs per block). (256,4) reg clamp.
// ---------------------------------------------------------------------------
__global__ __launch_bounds__(256, 4) void kG(
    const float* __restrict__ h0, const unsigned short* __restrict__ Wre,
    float* __restrict__ G)
{
    __shared__ alignas(16) unsigned short Bl[8192];
    __shared__ alignas(16) unsigned short Al[8192];
    char* Blc = (char*)Bl; char* Alc = (char*)Al;
    const int tid = threadIdx.x;
    const int l = tid & 63, wid = tid >> 6;
    const int og = l >> 4, lr = l & 15;
    const int wr = wid >> 1, wc2 = wid & 1;
    const int ct = blockIdx.x & 3, mt = (blockIdx.x >> 2) & 31, hn = blockIdx.x >> 7;
    const long g0 = (long)mt * 128;
    const int c0 = ct << 7;
    const int r0 = tid >> 2, ogk = tid & 3;

    f32x4 acc[4][4];
    #pragma unroll
    for (int m = 0; m < 4; ++m)
        #pragma unroll
        for (int n = 0; n < 4; ++n) acc[m][n] = (f32x4)(0.f);

    for (int kt2 = 0; kt2 < 2; ++kt2) {
        __syncthreads();
        #pragma unroll
        for (int s = 0; s < 2; ++s) {
            const int kt = (hn << 2) + (kt2 << 1) + s;
            const char* gB = (const char*)Wre + ((long)(ct * 16 + kt) << 13);
            char* BlS = Blc + (s << 13);
            gload_lds16(gB + (wid << 10) + (l << 4),        BlS + (wid << 10));
            gload_lds16(gB + 4096 + (wid << 10) + (l << 4), BlS + 4096 + (wid << 10));
            const int kb = kt << 5;
            const float* xr0 = &h0[(g0 + r0) * 512 + kb + (ogk << 3)];
            const float* xr1 = &h0[(g0 + r0 + 64) * 512 + kb + (ogk << 3)];
            float4 a0 = *(const float4*)xr0, a1 = *(const float4*)(xr0 + 4);
            float4 b0 = *(const float4*)xr1, b1 = *(const float4*)(xr1 + 4);
            ulonglong2 w0, w1;
            w0.x = pack4bf(a0); w0.y = pack4bf(a1);
            w1.x = pack4bf(b0); w1.y = pack4bf(b1);
            char* AlS = Alc + (s << 13);
            *(ulonglong2*)(AlS + AOFF(ogk, r0))      = w0;
            *(ulonglong2*)(AlS + AOFF(ogk, r0 + 64)) = w1;
        }
        __syncthreads();

        #pragma unroll
        for (int s = 0; s < 2; ++s) {
            const char* AlS = Alc + (s << 13);
            const char* BlS = Blc + (s << 13);
            bf16x8 afr[4], bfr[4];
            #pragma unroll
            for (int m = 0; m < 4; ++m)
                afr[m] = *(const bf16x8*)(AlS + AOFF(og, (wr << 6) + (m << 4) + lr));
            #pragma unroll
            for (int n = 0; n < 4; ++n)
                bfr[n] = *(const bf16x8*)(BlS + BOFF(og, (wc2 << 6) + (n << 4) + lr));
            #pragma unroll
            for (int m = 0; m < 4; ++m)
                #pragma unroll
                for (int n = 0; n < 4; ++n)
                    acc[m][n] = __builtin_amdgcn_mfma_f32_16x16x32_bf16(afr[m], bfr[n], acc[m][n], 0, 0, 0);
        }
    }

    float* Gh = G + ((long)hn << 21);
    #pragma unroll
    for (int m = 0; m < 4; ++m) {
        const long rb = g0 + (wr << 6) + (m << 4) + (og << 2);
        #pragma unroll
        for (int n = 0; n < 4; ++n) {
            const int col = c0 + (wc2 << 6) + (n << 4) + lr;
            #pragma unroll
            for (int j = 0; j < 4; ++j)
                Gh[(rb + j) * 512 + col] = acc[m][n][j];
        }
    }
}

// ---------------------------------------------------------------------------
// gemm2: out = B0 @ Wout^T + p.G  (phase C in epilogue). Both operands via
// pure global_load_lds, two subtiles per barrier-pair. XCD-grouped decode.
// (256,4): clamp to 128 unified regs -> 4 waves/SIMD (mirrors gemm1's R11 win).
// ---------------------------------------------------------------------------
__global__ __launch_bounds__(256, 4) void gemm2(
    const unsigned short* __restrict__ A2, const unsigned short* __restrict__ Wre,
    const float* __restrict__ G, const float* __restrict__ p_buf,
    float* __restrict__ out)
{
    __shared__ alignas(16) unsigned short Bl[8192];
    __shared__ alignas(16) unsigned short Al[8192];
    __shared__ float pS[512];
    char* Blc = (char*)Bl; char* Alc = (char*)Al;
    const int tid = threadIdx.x;
    const int l = tid & 63, wid = tid >> 6;
    const int og = l >> 4, lr = l & 15;
    const int wr = wid >> 1, wc2 = wid & 1;
    XCD_DECODE(mt, ct)
    const long t0 = (long)mt * 128;
    const int c0 = ct << 7;

    pS[tid]       = p_buf[t0 * 4 + tid];
    pS[tid + 256] = p_buf[t0 * 4 + 256 + tid];

    f32x4 acc[4][4];
    #pragma unroll
    for (int m = 0; m < 4; ++m)
        #pragma unroll
        for (int n = 0; n < 4; ++n) acc[m][n] = (f32x4)(0.f);

    for (int kt2 = 0; kt2 < 8; ++kt2) {
        __syncthreads();
        #pragma unroll
        for (int s = 0; s < 2; ++s) {
            const int kt = (kt2 << 1) + s;
            const char* gB = (const char*)Wre + ((long)(ct * 16 + kt) << 13);
            const char* gA = (const char*)A2 + ((long)(mt * 16 + kt) << 13);
            char* BlS = Blc + (s << 13);
            char* AlS = Alc + (s << 13);
            gload_lds16(gB + (wid << 10) + (l << 4),        BlS + (wid << 10));
            gload_lds16(gB + 4096 + (wid << 10) + (l << 4), BlS + 4096 + (wid << 10));
            gload_lds16(gA + (wid << 10) + (l << 4),        AlS + (wid << 10));
            gload_lds16(gA + 4096 + (wid << 10) + (l << 4), AlS + 4096 + (wid << 10));
        }
        __syncthreads();

        #pragma unroll
        for (int s = 0; s < 2; ++s) {
            const char* AlS = Alc + (s << 13);
            const char* BlS = Blc + (s << 13);
            bf16x8 afr[4], bfr[4];
            #pragma unroll
            for (int m = 0; m < 4; ++m)
                afr[m] = *(const bf16x8*)(AlS + BOFF(og, (wr << 6) + (m << 4) + lr));
            #pragma unroll
            for (int n = 0; n < 4; ++n)
                bfr[n] = *(const bf16x8*)(BlS + BOFF(og, (wc2 << 6) + (n << 4) + lr));
            #pragma unroll
            for (int m = 0; m < 4; ++m)
                #pragma unroll
                for (int n = 0; n < 4; ++n)
                    acc[m][n] = __builtin_amdgcn_mfma_f32_16x16x32_bf16(afr[m], bfr[n], acc[m][n], 0, 0, 0);
        }
    }

    #pragma unroll
    for (int m = 0; m < 4; ++m) {
        const long gcm = (t0 >> 4) + (wr << 2) + m;
        #pragma unroll
        for (int n = 0; n < 4; ++n) {
            const int col = c0 + (wc2 << 6) + (n << 4) + lr;
            const float g0v = G[gcm * 512 + col];
            const float g1v = G[(1L << 21) + gcm * 512 + col];
            const float g2v = G[(2L << 21) + gcm * 512 + col];
            const float g3v = G[(3L << 21) + gcm * 512 + col];
            #pragma unroll
            for (int j = 0; j < 4; ++j) {
                const int rl = (wr << 6) + (m << 4) + (og << 2) + j;
                const float add = pS[rl*4]*g0v + pS[rl*4+1]*g1v + pS[rl*4+2]*g2v + pS[rl*4+3]*g3v;
                out[(t0 + rl) * 512 + col] = acc[m][n][j] + add;
            }
        }
    }
}

extern "C" void kernel_launch(void* const* d_in, const int* in_sizes, int n_in,
                              void* d_out, int out_size, void* d_ws, size_t ws_size,
                              hipStream_t stream) {
    const float* x       = (const float*)d_in[0];
    const float* h       = (const float*)d_in[1];
    const float* Win     = (const float*)d_in[2];
    const float* gamma   = (const float*)d_in[3];
    const float* beta    = (const float*)d_in[4];
    const float* Wg      = (const float*)d_in[5];
    const float* bg      = (const float*)d_in[6];
    const float* eig_raw = (const float*)d_in[7];
    const float* Wout    = (const float*)d_in[8];

    float* out    = (float*)d_out;
    float* h_last = out + (long)NTOK * DH_;
    unsigned short* xpb = (unsigned short*)d_out;   // bf16 xp, dead before gemm2 writes

    float* ws     = (float*)d_ws;
    float* p_buf  = ws;                            //  262144 f
    float* h0_buf = ws + 262144;                   // 2097152 f
    float* B15    = ws + 2359296;                  // 2097152 f
    float* G      = ws + 4456448;                  // 8388608 f
    unsigned short* WreA = (unsigned short*)(ws + 12845056);  // 262144 us
    unsigned short* WreB = WreA + 262144;                     // 262144 us
    unsigned short* A2   = (unsigned short*)(ws + 13107200);  // 33554432 us

    // scan scratch aliases G (G is produced by kG AFTER the scan finishes)
    float* Pg  = G;                 // 131072 f
    float* Qg  = G + 131072;        // 131072 f
    float* h0g = G + 262144;        // 131072 f

    k0_convert<<<1024, 256, 0, stream>>>(Win, Wout, WreA, WreB);
    gemm1<<<2048, 256, 0, stream>>>(x, WreA, xpb);
    k_lnA<<<NTOK/16, 256, 0, stream>>>(xpb, gamma, beta, Wg, bg, eig_raw,
                                       A2, B15, p_buf);
    k3a_compose<<<512, 256, 0, stream>>>(p_buf, B15, Pg, Qg);
    k3b_scan<<<16, 256, 0, stream>>>(Pg, Qg, h, h0g, h_last);
    k3c_expand<<<512, 256, 0, stream>>>(p_buf, B15, h0g, h0_buf);
    kG<<<512, 256, 0, stream>>>(h0_buf, WreB, G);
    gemm2<<<2048, 256, 0, stream>>>(A2, WreB, G, p_buf, out);
}

// Round 14
// 210.258 us; speedup vs baseline: 1.0103x; 1.0103x over previous
//
#include <hip/hip_runtime.h>
#include <hip/hip_bf16.h>
#include <math.h>

#define B_    8
#define S_    8192
#define DIN_  512
#define DH_   512
#define HN_   4
#define HD_   128
#define CHUNK_ 16
#define NC_   (S_/CHUNK_)
#define NTOK  (B_*S_)

typedef __bf16 bf16x8 __attribute__((ext_vector_type(8)));
typedef float  f32x4  __attribute__((ext_vector_type(4)));

__device__ __forceinline__ float sigmoidf_(float z) { return 1.0f / (1.0f + expf(-z)); }

__device__ __forceinline__ unsigned short f2bf(float f) {
    union { float f; unsigned u; } v; v.f = f;
    unsigned u = v.u;
    u += 0x7fffu + ((u >> 16) & 1u);   // RNE
    return (unsigned short)(u >> 16);
}
__device__ __forceinline__ float bf2f(unsigned short s) {
    union { unsigned u; float f; } c; c.u = ((unsigned)s) << 16; return c.f;
}
// compiler casts -> v_cvt_pk_bf16_f32 (RNE, same numerics as manual f2bf)
__device__ __forceinline__ unsigned long long pack4bf(float4 a) {
    union { __bf16 h[4]; unsigned long long u; } c;
    c.h[0] = (__bf16)a.x; c.h[1] = (__bf16)a.y;
    c.h[2] = (__bf16)a.z; c.h[3] = (__bf16)a.w;
    return c.u;
}
__device__ __forceinline__ void gload_lds16(const void* g, void* lds) {
    __builtin_amdgcn_global_load_lds(
        (const __attribute__((address_space(1))) unsigned int*)g,
        (__attribute__((address_space(3))) unsigned int*)lds, 16, 0, 0);
}

// A-tile LDS byte offset within an 8KB subtile, XOR-swizzled (both sides)
#define AOFF(og, r) ((((og) << 11) + ((r) << 4)) ^ ((og) << 5))
// Linear subtile byte offset (global_load_lds dest / pre-packed operands)
#define BOFF(og, c) (((og) << 11) + ((c) << 4))

// XCD-grouping decode: the 4 ct-blocks of an mt land on the SAME XCD,
// temporally adjacent (default dispatch: xcd = blockIdx % 8).
#define XCD_DECODE(mt, ct)                        \
    const int _bid = blockIdx.x;                  \
    const int _j = _bid >> 3;                     \
    const int mt = ((_j >> 2) << 3) + (_bid & 7); \
    const int ct = _j & 3;

// ---------------------------------------------------------------------------
// k0: W (f32 [512][512], row=outcol) -> bf16 tiled layout (8KB tiles):
//   half-index = (((ct*16 + kt)*4 + og) << 10) + (c << 3) + kk
// ---------------------------------------------------------------------------
__global__ __launch_bounds__(256) void k0_convert(
    const float* __restrict__ Win, const float* __restrict__ Wout,
    unsigned short* __restrict__ WreA, unsigned short* __restrict__ WreB)
{
    int idx = blockIdx.x * 256 + threadIdx.x;
    if (idx < 262144) {
        int c_g = idx >> 9, k = idx & 511;
        int dst = ((((c_g >> 7) * 16 + (k >> 5)) * 4 + ((k >> 3) & 3)) << 10)
                + ((c_g & 127) << 3) + (k & 7);
        WreA[dst] = f2bf(Win[idx]);
        WreB[dst] = f2bf(Wout[idx]);
    }
}

// ---------------------------------------------------------------------------
// gemm1: xpb = bf16(x @ Win^T). 128x128 tile, 4 waves 2x2, TWO 32-k subtiles
// per barrier-pair, 32 KB LDS. (256,4) reg clamp -> 4 waves/SIMD.  [R11]
// ---------------------------------------------------------------------------
__global__ __launch_bounds__(256, 4) void gemm1(
    const float* __restrict__ x, const unsigned short* __restrict__ Wre,
    unsigned short* __restrict__ xpb)
{
    __shared__ alignas(16) unsigned short Bl[8192];  // 16 KB: 2 subtiles
    __shared__ alignas(16) unsigned short Al[8192];  // 16 KB: 2 subtiles
    char* Blc = (char*)Bl; char* Alc = (char*)Al;
    const int tid = threadIdx.x;
    const int l = tid & 63, wid = tid >> 6;
    const int og = l >> 4, lr = l & 15;
    const int wr = wid >> 1, wc2 = wid & 1;
    XCD_DECODE(mt, ct)
    const long t0 = (long)mt * 128;
    const int c0 = ct << 7;
    const int r0 = tid >> 2, ogk = tid & 3;

    f32x4 acc[4][4];
    #pragma unroll
    for (int m = 0; m < 4; ++m)
        #pragma unroll
        for (int n = 0; n < 4; ++n) acc[m][n] = (f32x4)(0.f);

    for (int kt2 = 0; kt2 < 8; ++kt2) {
        __syncthreads();
        #pragma unroll
        for (int s = 0; s < 2; ++s) {
            const int kt = (kt2 << 1) + s;
            const char* gB = (const char*)Wre + ((long)(ct * 16 + kt) << 13);
            char* BlS = Blc + (s << 13);
            gload_lds16(gB + (wid << 10) + (l << 4),        BlS + (wid << 10));
            gload_lds16(gB + 4096 + (wid << 10) + (l << 4), BlS + 4096 + (wid << 10));
            const int kb = kt << 5;
            const float* xr0 = &x[(t0 + r0) * 512 + kb + (ogk << 3)];
            const float* xr1 = &x[(t0 + r0 + 64) * 512 + kb + (ogk << 3)];
            float4 a0 = *(const float4*)xr0, a1 = *(const float4*)(xr0 + 4);
            float4 b0 = *(const float4*)xr1, b1 = *(const float4*)(xr1 + 4);
            ulonglong2 w0, w1;
            w0.x = pack4bf(a0); w0.y = pack4bf(a1);
            w1.x = pack4bf(b0); w1.y = pack4bf(b1);
            char* AlS = Alc + (s << 13);
            *(ulonglong2*)(AlS + AOFF(ogk, r0))      = w0;
            *(ulonglong2*)(AlS + AOFF(ogk, r0 + 64)) = w1;
        }
        __syncthreads();

        #pragma unroll
        for (int s = 0; s < 2; ++s) {
            const char* AlS = Alc + (s << 13);
            const char* BlS = Blc + (s << 13);
            bf16x8 afr[4], bfr[4];
            #pragma unroll
            for (int m = 0; m < 4; ++m)
                afr[m] = *(const bf16x8*)(AlS + AOFF(og, (wr << 6) + (m << 4) + lr));
            #pragma unroll
            for (int n = 0; n < 4; ++n)
                bfr[n] = *(const bf16x8*)(BlS + BOFF(og, (wc2 << 6) + (n << 4) + lr));
            #pragma unroll
            for (int m = 0; m < 4; ++m)
                #pragma unroll
                for (int n = 0; n < 4; ++n)
                    acc[m][n] = __builtin_amdgcn_mfma_f32_16x16x32_bf16(afr[m], bfr[n], acc[m][n], 0, 0, 0);
        }
    }

    #pragma unroll
    for (int m = 0; m < 4; ++m) {
        const long rb = t0 + (wr << 6) + (m << 4) + (og << 2);
        #pragma unroll
        for (int n = 0; n < 4; ++n) {
            const int col = c0 + (wc2 << 6) + (n << 4) + lr;
            #pragma unroll
            for (int j = 0; j < 4; ++j)
                xpb[(rb + j) * 512 + col] = f2bf(acc[m][n][j]);
        }
    }
}

// ---------------------------------------------------------------------------
// k_lnA: block = 1 chunk (16 tokens), token-parallel (16 lanes/token). [R11]
// ---------------------------------------------------------------------------
__global__ __launch_bounds__(256) void k_lnA(
    const unsigned short* __restrict__ xpb,
    const float* __restrict__ gamma, const float* __restrict__ beta,
    const float* __restrict__ Wg, const float* __restrict__ bg,
    const float* __restrict__ eig_raw,
    unsigned short* __restrict__ A2, float* __restrict__ B15,
    float* __restrict__ p_buf)
{
    __shared__ float bnS[16][512];   // 32 KB
    __shared__ float WgL[8][512];    // 16 KB
    __shared__ float qS[16][4];
    __shared__ float rqS[16][4];
    __shared__ float aS[16][4];

    const int tid = threadIdx.x;
    const int l = tid & 63, w = tid >> 6;
    const int lg = l >> 4;
    const int li = l & 15;
    const int r  = (w << 2) + lg;
    const long t0 = (long)blockIdx.x * 16;
    const long tok = t0 + r;

    float4 v[8];
    #pragma unroll
    for (int jj = 0; jj < 8; ++jj) {
        const ushort4 u = *(const ushort4*)&xpb[tok * 512 + (jj << 6) + (li << 2)];
        v[jj] = make_float4(bf2f(u.x), bf2f(u.y), bf2f(u.z), bf2f(u.w));
    }

    #pragma unroll
    for (int i = 0; i < 4; ++i)
        ((float4*)WgL)[tid + 256 * i] = ((const float4*)Wg)[tid + 256 * i];
    __syncthreads();

    float s1 = 0.f, s2 = 0.f;
    #pragma unroll
    for (int jj = 0; jj < 8; ++jj) {
        s1 += v[jj].x + v[jj].y + v[jj].z + v[jj].w;
        s2 += v[jj].x*v[jj].x + v[jj].y*v[jj].y + v[jj].z*v[jj].z + v[jj].w*v[jj].w;
    }
    #pragma unroll
    for (int o = 1; o < 16; o <<= 1) { s1 += __shfl_xor(s1, o, 64); s2 += __shfl_xor(s2, o, 64); }
    const float mean = s1 * (1.f/512.f);
    const float var  = s2 * (1.f/512.f) - mean*mean;
    const float rstd = 1.0f / sqrtf(var + 1e-5f);

    #pragma unroll
    for (int jj = 0; jj < 8; ++jj) {
        const float4 g = *(const float4*)&gamma[(jj << 6) + (li << 2)];
        const float4 b = *(const float4*)&beta[(jj << 6) + (li << 2)];
        v[jj].x = (v[jj].x - mean)*rstd*g.x + b.x;
        v[jj].y = (v[jj].y - mean)*rstd*g.y + b.y;
        v[jj].z = (v[jj].z - mean)*rstd*g.z + b.z;
        v[jj].w = (v[jj].w - mean)*rstd*g.w + b.w;
    }

    float gt[8];
    #pragma unroll
    for (int g = 0; g < 8; ++g) {
        float p = 0.f;
        #pragma unroll
        for (int jj = 0; jj < 8; ++jj) {
            const float4 wv = *(const float4*)&WgL[g][(jj << 6) + (li << 2)];
            p = fmaf(v[jj].x, wv.x, p); p = fmaf(v[jj].y, wv.y, p);
            p = fmaf(v[jj].z, wv.z, p); p = fmaf(v[jj].w, wv.w, p);
        }
        #pragma unroll
        for (int o = 1; o < 16; o <<= 1) p += __shfl_xor(p, o, 64);
        gt[g] = p + bg[g];
    }

    const float bt[4] = {sigmoidf_(gt[4]), sigmoidf_(gt[5]), sigmoidf_(gt[6]), sigmoidf_(gt[7])};
    #pragma unroll
    for (int jj = 0; jj < 8; ++jj) {
        const float b = bt[jj >> 1];
        *(float4*)&bnS[r][(jj << 6) + (li << 2)] =
            make_float4(b*v[jj].x, b*v[jj].y, b*v[jj].z, b*v[jj].w);
    }
    if (li < 4) aS[r][li] = tanhf(eig_raw[li]) * sigmoidf_(gt[li]);
    __syncthreads();

    if (tid < 4) {
        const int n = tid;
        float p = 1.f;
        #pragma unroll
        for (int t = 0; t < 16; ++t) {
            p *= aS[t][n];
            p_buf[(t0 + t) * 4 + n] = p;
            const float q = fmaxf(p, 1e-6f);
            qS[t][n] = q;
            rqS[t][n] = 1.0f / q;
        }
    }
    __syncthreads();

    #pragma unroll
    for (int cc = 0; cc < 2; ++cc) {
        const int c = tid + (cc << 8);
        const int n = c >> 7;
        float s = 0.f;
        #pragma unroll
        for (int t = 0; t < 16; ++t) {
            s = fmaf(bnS[t][c], rqS[t][n], s);
            const float vv = qS[t][n] * s;
            bnS[t][c] = vv;
            if (t == 15) B15[blockIdx.x * 512 + c] = vv;
        }
    }
    __syncthreads();

    const long mtb = t0 >> 7;
    #pragma unroll
    for (int i = 0; i < 4; ++i) {
        const int slot = (i << 8) + tid;
        const int t = slot >> 6, oct = slot & 63;
        const float4 va = *(const float4*)&bnS[t][oct << 3];
        const float4 vb = *(const float4*)&bnS[t][(oct << 3) + 4];
        const int rr = (int)((t0 + t) & 127);
        const long idx = (((mtb * 16 + (oct >> 2)) * 4 + (oct & 3)) << 10) + (rr << 3);
        ulonglong2 wv; wv.x = pack4bf(va); wv.y = pack4bf(vb);
        *(ulonglong2*)&A2[idx] = wv;
    }
}

// ---------------------------------------------------------------------------
// Two-level parallel scan over 512 chunk carries (groups of 16). [R11]
// ---------------------------------------------------------------------------
__global__ __launch_bounds__(256) void k3a_compose(
    const float* __restrict__ p_buf, const float* __restrict__ B15,
    float* __restrict__ Pg, float* __restrict__ Qg)
{
    const int gid = blockIdx.x * 256 + threadIdx.x;   // 0..131071
    const int c = gid & 511, g = (gid >> 9) & 31, b = gid >> 14;
    const int n = c >> 7;
    float P = 1.f, Q = 0.f;
    #pragma unroll
    for (int j = 0; j < 16; ++j) {
        const int ch = (g << 4) + j;
        const long gc = (long)b * NC_ + ch;
        const long sE = (long)b * S_ + (long)ch * CHUNK_ + (CHUNK_ - 1);
        const float p15 = p_buf[sE * HN_ + n];
        const float b15 = B15[gc * 512 + c];
        P *= p15;
        Q = fmaf(p15, Q, b15);
    }
    Pg[(long)gid] = P;
    Qg[(long)gid] = Q;
}

__global__ __launch_bounds__(256) void k3b_scan(
    const float* __restrict__ Pg, const float* __restrict__ Qg,
    const float* __restrict__ h_in, float* __restrict__ h0g,
    float* __restrict__ h_last)
{
    const int tid = blockIdx.x * blockDim.x + threadIdx.x; // 0..4095
    const int b = tid >> 9, c = tid & 511;
    float h = h_in[b * DH_ + c];
    for (int g = 0; g < 32; ++g) {
        const long i = ((long)(b * 32 + g)) * 512 + c;
        h0g[i] = h;
        h = fmaf(Pg[i], h, Qg[i]);
    }
    h_last[b * DH_ + c] = h;
}

__global__ __launch_bounds__(256) void k3c_expand(
    const float* __restrict__ p_buf, const float* __restrict__ B15,
    const float* __restrict__ h0g, float* __restrict__ h0_buf)
{
    const int gid = blockIdx.x * 256 + threadIdx.x;   // 0..131071
    const int c = gid & 511, g = (gid >> 9) & 31, b = gid >> 14;
    const int n = c >> 7;
    float h = h0g[(long)gid];
    #pragma unroll
    for (int j = 0; j < 16; ++j) {
        const int ch = (g << 4) + j;
        const long gc = (long)b * NC_ + ch;
        h0_buf[gc * 512 + c] = h;
        const long sE = (long)b * S_ + (long)ch * CHUNK_ + (CHUNK_ - 1);
        h = fmaf(p_buf[sE * HN_ + n], h, B15[gc * 512 + c]);
    }
}

// ---------------------------------------------------------------------------
// kG: G[hn][gc][col] = sum_{k in hn slice} h0[gc][k] * Wout[col][k]. [R11]
// ---------------------------------------------------------------------------
__global__ __launch_bounds__(256) void kG(
    const float* __restrict__ h0, const unsigned short* __restrict__ Wre,
    float* __restrict__ G)
{
    __shared__ alignas(16) unsigned short Bl[8192];
    __shared__ alignas(16) unsigned short Al[8192];
    char* Blc = (char*)Bl; char* Alc = (char*)Al;
    const int tid = threadIdx.x;
    const int l = tid & 63, wid = tid >> 6;
    const int og = l >> 4, lr = l & 15;
    const int wr = wid >> 1, wc2 = wid & 1;
    const int ct = blockIdx.x & 3, mt = (blockIdx.x >> 2) & 31, hn = blockIdx.x >> 7;
    const long g0 = (long)mt * 128;
    const int c0 = ct << 7;
    const int r0 = tid >> 2, ogk = tid & 3;

    f32x4 acc[4][4];
    #pragma unroll
    for (int m = 0; m < 4; ++m)
        #pragma unroll
        for (int n = 0; n < 4; ++n) acc[m][n] = (f32x4)(0.f);

    for (int kt2 = 0; kt2 < 2; ++kt2) {
        __syncthreads();
        #pragma unroll
        for (int s = 0; s < 2; ++s) {
            const int kt = (hn << 2) + (kt2 << 1) + s;
            const char* gB = (const char*)Wre + ((long)(ct * 16 + kt) << 13);
            char* BlS = Blc + (s << 13);
            gload_lds16(gB + (wid << 10) + (l << 4),        BlS + (wid << 10));
            gload_lds16(gB + 4096 + (wid << 10) + (l << 4), BlS + 4096 + (wid << 10));
            const int kb = kt << 5;
            const float* xr0 = &h0[(g0 + r0) * 512 + kb + (ogk << 3)];
            const float* xr1 = &h0[(g0 + r0 + 64) * 512 + kb + (ogk << 3)];
            float4 a0 = *(const float4*)xr0, a1 = *(const float4*)(xr0 + 4);
            float4 b0 = *(const float4*)xr1, b1 = *(const float4*)(xr1 + 4);
            ulonglong2 w0, w1;
            w0.x = pack4bf(a0); w0.y = pack4bf(a1);
            w1.x = pack4bf(b0); w1.y = pack4bf(b1);
            char* AlS = Alc + (s << 13);
            *(ulonglong2*)(AlS + AOFF(ogk, r0))      = w0;
            *(ulonglong2*)(AlS + AOFF(ogk, r0 + 64)) = w1;
        }
        __syncthreads();

        #pragma unroll
        for (int s = 0; s < 2; ++s) {
            const char* AlS = Alc + (s << 13);
            const char* BlS = Blc + (s << 13);
            bf16x8 afr[4], bfr[4];
            #pragma unroll
            for (int m = 0; m < 4; ++m)
                afr[m] = *(const bf16x8*)(AlS + AOFF(og, (wr << 6) + (m << 4) + lr));
            #pragma unroll
            for (int n = 0; n < 4; ++n)
                bfr[n] = *(const bf16x8*)(BlS + BOFF(og, (wc2 << 6) + (n << 4) + lr));
            #pragma unroll
            for (int m = 0; m < 4; ++m)
                #pragma unroll
                for (int n = 0; n < 4; ++n)
                    acc[m][n] = __builtin_amdgcn_mfma_f32_16x16x32_bf16(afr[m], bfr[n], acc[m][n], 0, 0, 0);
        }
    }

    float* Gh = G + ((long)hn << 21);
    #pragma unroll
    for (int m = 0; m < 4; ++m) {
        const long rb = g0 + (wr << 6) + (m << 4) + (og << 2);
        #pragma unroll
        for (int n = 0; n < 4; ++n) {
            const int col = c0 + (wc2 << 6) + (n << 4) + lr;
            #pragma unroll
            for (int j = 0; j < 4; ++j)
                Gh[(rb + j) * 512 + col] = acc[m][n][j];
        }
    }
}

// ---------------------------------------------------------------------------
// gemm2: out = B0 @ Wout^T + p.G. COUNTED-VMCNT 3-BUFFER PIPELINE, race-fixed:
// pre-barrier wait is now "vmcnt(4) lgkmcnt(0)" — lgkmcnt(0) guarantees this
// wave's ds_reads of the previous tile have SAMPLED LDS before it signals the
// barrier (ISA: "s_barrier — s_waitcnt first if data dep"), so STAGE2 of
// tile kt+2 (issued by any wave after the barrier) cannot overwrite data
// still pending in another wave's LDS-read queue. vmcnt stays >0 mid-loop.
// ---------------------------------------------------------------------------
__global__ __launch_bounds__(256) void gemm2(
    const unsigned short* __restrict__ A2, const unsigned short* __restrict__ Wre,
    const float* __restrict__ G, const float* __restrict__ p_buf,
    float* __restrict__ out)
{
    __shared__ alignas(16) unsigned short Bl[3][4096];   // 3 x 8 KB
    __shared__ alignas(16) unsigned short Al[3][4096];   // 3 x 8 KB
    __shared__ float pS[512];
    const int tid = threadIdx.x;
    const int l = tid & 63, wid = tid >> 6;
    const int og = l >> 4, lr = l & 15;
    const int wr = wid >> 1, wc2 = wid & 1;
    XCD_DECODE(mt, ct)
    const long t0 = (long)mt * 128;
    const int c0 = ct << 7;

    pS[tid]       = p_buf[t0 * 4 + tid];
    pS[tid + 256] = p_buf[t0 * 4 + 256 + tid];
    __syncthreads();   // drains everything; pipeline starts with vmcnt=0

    const char* gBbase = (const char*)Wre + ((long)(ct * 16) << 13);
    const char* gAbase = (const char*)A2  + ((long)(mt * 16) << 13);
    const int src_off = (wid << 10) + (l << 4);
    const int dst_off = (wid << 10);              // wave-uniform LDS base

#define STAGE2(kt, buf) do {                                               \
        const char* gB_ = gBbase + ((long)(kt) << 13);                     \
        const char* gA_ = gAbase + ((long)(kt) << 13);                     \
        gload_lds16(gB_ + src_off,        (char*)Bl[buf] + dst_off);       \
        gload_lds16(gB_ + 4096 + src_off, (char*)Bl[buf] + 4096 + dst_off);\
        gload_lds16(gA_ + src_off,        (char*)Al[buf] + dst_off);       \
        gload_lds16(gA_ + 4096 + src_off, (char*)Al[buf] + 4096 + dst_off);\
    } while (0)

    f32x4 acc[4][4];
    #pragma unroll
    for (int m = 0; m < 4; ++m)
        #pragma unroll
        for (int n = 0; n < 4; ++n) acc[m][n] = (f32x4)(0.f);

    // prologue: tiles 0 and 1 in flight (4 loads each)
    STAGE2(0, 0);
    STAGE2(1, 1);

    #pragma unroll
    for (int kt = 0; kt < 16; ++kt) {
        // tile kt landed (own 4 oldest loads done); own ds_reads sampled.
        if (kt < 15) asm volatile("s_waitcnt vmcnt(4) lgkmcnt(0)" ::: "memory");
        else         asm volatile("s_waitcnt vmcnt(0) lgkmcnt(0)" ::: "memory");
        __builtin_amdgcn_s_barrier();
        asm volatile("" ::: "memory");
        if (kt < 14) STAGE2(kt + 2, (kt + 2) % 3);

        const char* AlS = (const char*)Al[kt % 3];
        const char* BlS = (const char*)Bl[kt % 3];
        bf16x8 afr[4], bfr[4];
        #pragma unroll
        for (int m = 0; m < 4; ++m)
            afr[m] = *(const bf16x8*)(AlS + BOFF(og, (wr << 6) + (m << 4) + lr));
        #pragma unroll
        for (int n = 0; n < 4; ++n)
            bfr[n] = *(const bf16x8*)(BlS + BOFF(og, (wc2 << 6) + (n << 4) + lr));
        #pragma unroll
        for (int m = 0; m < 4; ++m)
            #pragma unroll
            for (int n = 0; n < 4; ++n)
                acc[m][n] = __builtin_amdgcn_mfma_f32_16x16x32_bf16(afr[m], bfr[n], acc[m][n], 0, 0, 0);
    }
#undef STAGE2

    #pragma unroll
    for (int m = 0; m < 4; ++m) {
        const long gcm = (t0 >> 4) + (wr << 2) + m;
        #pragma unroll
        for (int n = 0; n < 4; ++n) {
            const int col = c0 + (wc2 << 6) + (n << 4) + lr;
            const float g0v = G[gcm * 512 + col];
            const float g1v = G[(1L << 21) + gcm * 512 + col];
            const float g2v = G[(2L << 21) + gcm * 512 + col];
            const float g3v = G[(3L << 21) + gcm * 512 + col];
            #pragma unroll
            for (int j = 0; j < 4; ++j) {
                const int rl = (wr << 6) + (m << 4) + (og << 2) + j;
                const float add = pS[rl*4]*g0v + pS[rl*4+1]*g1v + pS[rl*4+2]*g2v + pS[rl*4+3]*g3v;
                out[(t0 + rl) * 512 + col] = acc[m][n][j] + add;
            }
        }
    }
}

extern "C" void kernel_launch(void* const* d_in, const int* in_sizes, int n_in,
                              void* d_out, int out_size, void* d_ws, size_t ws_size,
                              hipStream_t stream) {
    const float* x       = (const float*)d_in[0];
    const float* h       = (const float*)d_in[1];
    const float* Win     = (const float*)d_in[2];
    const float* gamma   = (const float*)d_in[3];
    const float* beta    = (const float*)d_in[4];
    const float* Wg      = (const float*)d_in[5];
    const float* bg      = (const float*)d_in[6];
    const float* eig_raw = (const float*)d_in[7];
    const float* Wout    = (const float*)d_in[8];

    float* out    = (float*)d_out;
    float* h_last = out + (long)NTOK * DH_;
    unsigned short* xpb = (unsigned short*)d_out;   // bf16 xp, dead before gemm2 writes

    float* ws     = (float*)d_ws;
    float* p_buf  = ws;                            //  262144 f
    float* h0_buf = ws + 262144;                   // 2097152 f
    float* B15    = ws + 2359296;                  // 2097152 f
    float* G      = ws + 4456448;                  // 8388608 f
    unsigned short* WreA = (unsigned short*)(ws + 12845056);  // 262144 us
    unsigned short* WreB = WreA + 262144;                     // 262144 us
    unsigned short* A2   = (unsigned short*)(ws + 13107200);  // 33554432 us

    // scan scratch aliases G (G is produced by kG AFTER the scan finishes)
    float* Pg  = G;                 // 131072 f
    float* Qg  = G + 131072;        // 131072 f
    float* h0g = G + 262144;        // 131072 f

    k0_convert<<<1024, 256, 0, stream>>>(Win, Wout, WreA, WreB);
    gemm1<<<2048, 256, 0, stream>>>(x, WreA, xpb);
    k_lnA<<<NTOK/16, 256, 0, stream>>>(xpb, gamma, beta, Wg, bg, eig_raw,
                                       A2, B15, p_buf);
    k3a_compose<<<512, 256, 0, stream>>>(p_buf, B15, Pg, Qg);
    k3b_scan<<<16, 256, 0, stream>>>(Pg, Qg, h, h0g, h_last);
    k3c_expand<<<512, 256, 0, stream>>>(p_buf, B15, h0g, h0_buf);
    kG<<<512, 256, 0, stream>>>(h0_buf, WreB, G);
    gemm2<<<2048, 256, 0, stream>>>(A2, WreB, G, p_buf, out);
}

// Round 15
// 204.908 us; speedup vs baseline: 1.0366x; 1.0261x over previous
//
#include <hip/hip_runtime.h>
#include <hip/hip_bf16.h>
#include <math.h>

#define B_    8
#define S_    8192
#define DIN_  512
#define DH_   512
#define HN_   4
#define HD_   128
#define CHUNK_ 16
#define NC_   (S_/CHUNK_)
#define NTOK  (B_*S_)

typedef __bf16 bf16x8 __attribute__((ext_vector_type(8)));
typedef float  f32x4  __attribute__((ext_vector_type(4)));

__device__ __forceinline__ float sigmoidf_(float z) { return 1.0f / (1.0f + expf(-z)); }

__device__ __forceinline__ unsigned short f2bf(float f) {
    union { float f; unsigned u; } v; v.f = f;
    unsigned u = v.u;
    u += 0x7fffu + ((u >> 16) & 1u);   // RNE
    return (unsigned short)(u >> 16);
}
__device__ __forceinline__ float bf2f(unsigned short s) {
    union { unsigned u; float f; } c; c.u = ((unsigned)s) << 16; return c.f;
}
// compiler casts -> v_cvt_pk_bf16_f32 (RNE, same numerics as manual f2bf)
__device__ __forceinline__ unsigned long long pack4bf(float4 a) {
    union { __bf16 h[4]; unsigned long long u; } c;
    c.h[0] = (__bf16)a.x; c.h[1] = (__bf16)a.y;
    c.h[2] = (__bf16)a.z; c.h[3] = (__bf16)a.w;
    return c.u;
}
__device__ __forceinline__ void gload_lds16(const void* g, void* lds) {
    __builtin_amdgcn_global_load_lds(
        (const __attribute__((address_space(1))) unsigned int*)g,
        (__attribute__((address_space(3))) unsigned int*)lds, 16, 0, 0);
}

// A-tile LDS byte offset within an 8KB subtile, XOR-swizzled (both sides)
#define AOFF(og, r) ((((og) << 11) + ((r) << 4)) ^ ((og) << 5))
// Linear subtile byte offset (global_load_lds dest / pre-packed operands)
#define BOFF(og, c) (((og) << 11) + ((c) << 4))

// XCD-grouping decode: the 4 ct-blocks of an mt land on the SAME XCD,
// temporally adjacent (default dispatch: xcd = blockIdx % 8).
#define XCD_DECODE(mt, ct)                        \
    const int _bid = blockIdx.x;                  \
    const int _j = _bid >> 3;                     \
    const int mt = ((_j >> 2) << 3) + (_bid & 7); \
    const int ct = _j & 3;

// ---------------------------------------------------------------------------
// k0: W (f32 [512][512], row=outcol) -> bf16 tiled layout (8KB tiles):
//   half-index = (((ct*16 + kt)*4 + og) << 10) + (c << 3) + kk
// ---------------------------------------------------------------------------
__global__ __launch_bounds__(256) void k0_convert(
    const float* __restrict__ Win, const float* __restrict__ Wout,
    unsigned short* __restrict__ WreA, unsigned short* __restrict__ WreB)
{
    int idx = blockIdx.x * 256 + threadIdx.x;
    if (idx < 262144) {
        int c_g = idx >> 9, k = idx & 511;
        int dst = ((((c_g >> 7) * 16 + (k >> 5)) * 4 + ((k >> 3) & 3)) << 10)
                + ((c_g & 127) << 3) + (k & 7);
        WreA[dst] = f2bf(Win[idx]);
        WreB[dst] = f2bf(Wout[idx]);
    }
}

// ---------------------------------------------------------------------------
// gemm1: xpb = bf16(x @ Win^T). 128x128 tile, 4 waves 2x2, TWO 32-k subtiles
// per barrier-pair, 32 KB LDS. (256,4) reg clamp -> 4 waves/SIMD.  [R11]
// ---------------------------------------------------------------------------
__global__ __launch_bounds__(256, 4) void gemm1(
    const float* __restrict__ x, const unsigned short* __restrict__ Wre,
    unsigned short* __restrict__ xpb)
{
    __shared__ alignas(16) unsigned short Bl[8192];  // 16 KB: 2 subtiles
    __shared__ alignas(16) unsigned short Al[8192];  // 16 KB: 2 subtiles
    char* Blc = (char*)Bl; char* Alc = (char*)Al;
    const int tid = threadIdx.x;
    const int l = tid & 63, wid = tid >> 6;
    const int og = l >> 4, lr = l & 15;
    const int wr = wid >> 1, wc2 = wid & 1;
    XCD_DECODE(mt, ct)
    const long t0 = (long)mt * 128;
    const int c0 = ct << 7;
    const int r0 = tid >> 2, ogk = tid & 3;

    f32x4 acc[4][4];
    #pragma unroll
    for (int m = 0; m < 4; ++m)
        #pragma unroll
        for (int n = 0; n < 4; ++n) acc[m][n] = (f32x4)(0.f);

    for (int kt2 = 0; kt2 < 8; ++kt2) {
        __syncthreads();
        #pragma unroll
        for (int s = 0; s < 2; ++s) {
            const int kt = (kt2 << 1) + s;
            const char* gB = (const char*)Wre + ((long)(ct * 16 + kt) << 13);
            char* BlS = Blc + (s << 13);
            gload_lds16(gB + (wid << 10) + (l << 4),        BlS + (wid << 10));
            gload_lds16(gB + 4096 + (wid << 10) + (l << 4), BlS + 4096 + (wid << 10));
            const int kb = kt << 5;
            const float* xr0 = &x[(t0 + r0) * 512 + kb + (ogk << 3)];
            const float* xr1 = &x[(t0 + r0 + 64) * 512 + kb + (ogk << 3)];
            float4 a0 = *(const float4*)xr0, a1 = *(const float4*)(xr0 + 4);
            float4 b0 = *(const float4*)xr1, b1 = *(const float4*)(xr1 + 4);
            ulonglong2 w0, w1;
            w0.x = pack4bf(a0); w0.y = pack4bf(a1);
            w1.x = pack4bf(b0); w1.y = pack4bf(b1);
            char* AlS = Alc + (s << 13);
            *(ulonglong2*)(AlS + AOFF(ogk, r0))      = w0;
            *(ulonglong2*)(AlS + AOFF(ogk, r0 + 64)) = w1;
        }
        __syncthreads();

        #pragma unroll
        for (int s = 0; s < 2; ++s) {
            const char* AlS = Alc + (s << 13);
            const char* BlS = Blc + (s << 13);
            bf16x8 afr[4], bfr[4];
            #pragma unroll
            for (int m = 0; m < 4; ++m)
                afr[m] = *(const bf16x8*)(AlS + AOFF(og, (wr << 6) + (m << 4) + lr));
            #pragma unroll
            for (int n = 0; n < 4; ++n)
                bfr[n] = *(const bf16x8*)(BlS + BOFF(og, (wc2 << 6) + (n << 4) + lr));
            #pragma unroll
            for (int m = 0; m < 4; ++m)
                #pragma unroll
                for (int n = 0; n < 4; ++n)
                    acc[m][n] = __builtin_amdgcn_mfma_f32_16x16x32_bf16(afr[m], bfr[n], acc[m][n], 0, 0, 0);
        }
    }

    #pragma unroll
    for (int m = 0; m < 4; ++m) {
        const long rb = t0 + (wr << 6) + (m << 4) + (og << 2);
        #pragma unroll
        for (int n = 0; n < 4; ++n) {
            const int col = c0 + (wc2 << 6) + (n << 4) + lr;
            #pragma unroll
            for (int j = 0; j < 4; ++j)
                xpb[(rb + j) * 512 + col] = f2bf(acc[m][n][j]);
        }
    }
}

// ---------------------------------------------------------------------------
// k_lnA: block = 1 chunk (16 tokens), token-parallel (16 lanes/token). [R11]
// ---------------------------------------------------------------------------
__global__ __launch_bounds__(256) void k_lnA(
    const unsigned short* __restrict__ xpb,
    const float* __restrict__ gamma, const float* __restrict__ beta,
    const float* __restrict__ Wg, const float* __restrict__ bg,
    const float* __restrict__ eig_raw,
    unsigned short* __restrict__ A2, float* __restrict__ B15,
    float* __restrict__ p_buf)
{
    __shared__ float bnS[16][512];   // 32 KB
    __shared__ float WgL[8][512];    // 16 KB
    __shared__ float qS[16][4];
    __shared__ float rqS[16][4];
    __shared__ float aS[16][4];

    const int tid = threadIdx.x;
    const int l = tid & 63, w = tid >> 6;
    const int lg = l >> 4;
    const int li = l & 15;
    const int r  = (w << 2) + lg;
    const long t0 = (long)blockIdx.x * 16;
    const long tok = t0 + r;

    float4 v[8];
    #pragma unroll
    for (int jj = 0; jj < 8; ++jj) {
        const ushort4 u = *(const ushort4*)&xpb[tok * 512 + (jj << 6) + (li << 2)];
        v[jj] = make_float4(bf2f(u.x), bf2f(u.y), bf2f(u.z), bf2f(u.w));
    }

    #pragma unroll
    for (int i = 0; i < 4; ++i)
        ((float4*)WgL)[tid + 256 * i] = ((const float4*)Wg)[tid + 256 * i];
    __syncthreads();

    float s1 = 0.f, s2 = 0.f;
    #pragma unroll
    for (int jj = 0; jj < 8; ++jj) {
        s1 += v[jj].x + v[jj].y + v[jj].z + v[jj].w;
        s2 += v[jj].x*v[jj].x + v[jj].y*v[jj].y + v[jj].z*v[jj].z + v[jj].w*v[jj].w;
    }
    #pragma unroll
    for (int o = 1; o < 16; o <<= 1) { s1 += __shfl_xor(s1, o, 64); s2 += __shfl_xor(s2, o, 64); }
    const float mean = s1 * (1.f/512.f);
    const float var  = s2 * (1.f/512.f) - mean*mean;
    const float rstd = 1.0f / sqrtf(var + 1e-5f);

    #pragma unroll
    for (int jj = 0; jj < 8; ++jj) {
        const float4 g = *(const float4*)&gamma[(jj << 6) + (li << 2)];
        const float4 b = *(const float4*)&beta[(jj << 6) + (li << 2)];
        v[jj].x = (v[jj].x - mean)*rstd*g.x + b.x;
        v[jj].y = (v[jj].y - mean)*rstd*g.y + b.y;
        v[jj].z = (v[jj].z - mean)*rstd*g.z + b.z;
        v[jj].w = (v[jj].w - mean)*rstd*g.w + b.w;
    }

    float gt[8];
    #pragma unroll
    for (int g = 0; g < 8; ++g) {
        float p = 0.f;
        #pragma unroll
        for (int jj = 0; jj < 8; ++jj) {
            const float4 wv = *(const float4*)&WgL[g][(jj << 6) + (li << 2)];
            p = fmaf(v[jj].x, wv.x, p); p = fmaf(v[jj].y, wv.y, p);
            p = fmaf(v[jj].z, wv.z, p); p = fmaf(v[jj].w, wv.w, p);
        }
        #pragma unroll
        for (int o = 1; o < 16; o <<= 1) p += __shfl_xor(p, o, 64);
        gt[g] = p + bg[g];
    }

    const float bt[4] = {sigmoidf_(gt[4]), sigmoidf_(gt[5]), sigmoidf_(gt[6]), sigmoidf_(gt[7])};
    #pragma unroll
    for (int jj = 0; jj < 8; ++jj) {
        const float b = bt[jj >> 1];
        *(float4*)&bnS[r][(jj << 6) + (li << 2)] =
            make_float4(b*v[jj].x, b*v[jj].y, b*v[jj].z, b*v[jj].w);
    }
    if (li < 4) aS[r][li] = tanhf(eig_raw[li]) * sigmoidf_(gt[li]);
    __syncthreads();

    if (tid < 4) {
        const int n = tid;
        float p = 1.f;
        #pragma unroll
        for (int t = 0; t < 16; ++t) {
            p *= aS[t][n];
            p_buf[(t0 + t) * 4 + n] = p;
            const float q = fmaxf(p, 1e-6f);
            qS[t][n] = q;
            rqS[t][n] = 1.0f / q;
        }
    }
    __syncthreads();

    #pragma unroll
    for (int cc = 0; cc < 2; ++cc) {
        const int c = tid + (cc << 8);
        const int n = c >> 7;
        float s = 0.f;
        #pragma unroll
        for (int t = 0; t < 16; ++t) {
            s = fmaf(bnS[t][c], rqS[t][n], s);
            const float vv = qS[t][n] * s;
            bnS[t][c] = vv;
            if (t == 15) B15[blockIdx.x * 512 + c] = vv;
        }
    }
    __syncthreads();

    const long mtb = t0 >> 7;
    #pragma unroll
    for (int i = 0; i < 4; ++i) {
        const int slot = (i << 8) + tid;
        const int t = slot >> 6, oct = slot & 63;
        const float4 va = *(const float4*)&bnS[t][oct << 3];
        const float4 vb = *(const float4*)&bnS[t][(oct << 3) + 4];
        const int rr = (int)((t0 + t) & 127);
        const long idx = (((mtb * 16 + (oct >> 2)) * 4 + (oct & 3)) << 10) + (rr << 3);
        ulonglong2 wv; wv.x = pack4bf(va); wv.y = pack4bf(vb);
        *(ulonglong2*)&A2[idx] = wv;
    }
}

// ---------------------------------------------------------------------------
// Two-level parallel scan over 512 chunk carries (groups of 16). [R11]
// ---------------------------------------------------------------------------
__global__ __launch_bounds__(256) void k3a_compose(
    const float* __restrict__ p_buf, const float* __restrict__ B15,
    float* __restrict__ Pg, float* __restrict__ Qg)
{
    const int gid = blockIdx.x * 256 + threadIdx.x;   // 0..131071
    const int c = gid & 511, g = (gid >> 9) & 31, b = gid >> 14;
    const int n = c >> 7;
    float P = 1.f, Q = 0.f;
    #pragma unroll
    for (int j = 0; j < 16; ++j) {
        const int ch = (g << 4) + j;
        const long gc = (long)b * NC_ + ch;
        const long sE = (long)b * S_ + (long)ch * CHUNK_ + (CHUNK_ - 1);
        const float p15 = p_buf[sE * HN_ + n];
        const float b15 = B15[gc * 512 + c];
        P *= p15;
        Q = fmaf(p15, Q, b15);
    }
    Pg[(long)gid] = P;
    Qg[(long)gid] = Q;
}

__global__ __launch_bounds__(256) void k3b_scan(
    const float* __restrict__ Pg, const float* __restrict__ Qg,
    const float* __restrict__ h_in, float* __restrict__ h0g,
    float* __restrict__ h_last)
{
    const int tid = blockIdx.x * blockDim.x + threadIdx.x; // 0..4095
    const int b = tid >> 9, c = tid & 511;
    float h = h_in[b * DH_ + c];
    for (int g = 0; g < 32; ++g) {
        const long i = ((long)(b * 32 + g)) * 512 + c;
        h0g[i] = h;
        h = fmaf(Pg[i], h, Qg[i]);
    }
    h_last[b * DH_ + c] = h;
}

__global__ __launch_bounds__(256) void k3c_expand(
    const float* __restrict__ p_buf, const float* __restrict__ B15,
    const float* __restrict__ h0g, float* __restrict__ h0_buf)
{
    const int gid = blockIdx.x * 256 + threadIdx.x;   // 0..131071
    const int c = gid & 511, g = (gid >> 9) & 31, b = gid >> 14;
    const int n = c >> 7;
    float h = h0g[(long)gid];
    #pragma unroll
    for (int j = 0; j < 16; ++j) {
        const int ch = (g << 4) + j;
        const long gc = (long)b * NC_ + ch;
        h0_buf[gc * 512 + c] = h;
        const long sE = (long)b * S_ + (long)ch * CHUNK_ + (CHUNK_ - 1);
        h = fmaf(p_buf[sE * HN_ + n], h, B15[gc * 512 + c]);
    }
}

// ---------------------------------------------------------------------------
// kG: G[hn][gc][col] = sum_{k in hn slice} h0[gc][k] * Wout[col][k]. [R11]
// ---------------------------------------------------------------------------
__global__ __launch_bounds__(256) void kG(
    const float* __restrict__ h0, const unsigned short* __restrict__ Wre,
    float* __restrict__ G)
{
    __shared__ alignas(16) unsigned short Bl[8192];
    __shared__ alignas(16) unsigned short Al[8192];
    char* Blc = (char*)Bl; char* Alc = (char*)Al;
    const int tid = threadIdx.x;
    const int l = tid & 63, wid = tid >> 6;
    const int og = l >> 4, lr = l & 15;
    const int wr = wid >> 1, wc2 = wid & 1;
    const int ct = blockIdx.x & 3, mt = (blockIdx.x >> 2) & 31, hn = blockIdx.x >> 7;
    const long g0 = (long)mt * 128;
    const int c0 = ct << 7;
    const int r0 = tid >> 2, ogk = tid & 3;

    f32x4 acc[4][4];
    #pragma unroll
    for (int m = 0; m < 4; ++m)
        #pragma unroll
        for (int n = 0; n < 4; ++n) acc[m][n] = (f32x4)(0.f);

    for (int kt2 = 0; kt2 < 2; ++kt2) {
        __syncthreads();
        #pragma unroll
        for (int s = 0; s < 2; ++s) {
            const int kt = (hn << 2) + (kt2 << 1) + s;
            const char* gB = (const char*)Wre + ((long)(ct * 16 + kt) << 13);
            char* BlS = Blc + (s << 13);
            gload_lds16(gB + (wid << 10) + (l << 4),        BlS + (wid << 10));
            gload_lds16(gB + 4096 + (wid << 10) + (l << 4), BlS + 4096 + (wid << 10));
            const int kb = kt << 5;
            const float* xr0 = &h0[(g0 + r0) * 512 + kb + (ogk << 3)];
            const float* xr1 = &h0[(g0 + r0 + 64) * 512 + kb + (ogk << 3)];
            float4 a0 = *(const float4*)xr0, a1 = *(const float4*)(xr0 + 4);
            float4 b0 = *(const float4*)xr1, b1 = *(const float4*)(xr1 + 4);
            ulonglong2 w0, w1;
            w0.x = pack4bf(a0); w0.y = pack4bf(a1);
            w1.x = pack4bf(b0); w1.y = pack4bf(b1);
            char* AlS = Alc + (s << 13);
            *(ulonglong2*)(AlS + AOFF(ogk, r0))      = w0;
            *(ulonglong2*)(AlS + AOFF(ogk, r0 + 64)) = w1;
        }
        __syncthreads();

        #pragma unroll
        for (int s = 0; s < 2; ++s) {
            const char* AlS = Alc + (s << 13);
            const char* BlS = Blc + (s << 13);
            bf16x8 afr[4], bfr[4];
            #pragma unroll
            for (int m = 0; m < 4; ++m)
                afr[m] = *(const bf16x8*)(AlS + AOFF(og, (wr << 6) + (m << 4) + lr));
            #pragma unroll
            for (int n = 0; n < 4; ++n)
                bfr[n] = *(const bf16x8*)(BlS + BOFF(og, (wc2 << 6) + (n << 4) + lr));
            #pragma unroll
            for (int m = 0; m < 4; ++m)
                #pragma unroll
                for (int n = 0; n < 4; ++n)
                    acc[m][n] = __builtin_amdgcn_mfma_f32_16x16x32_bf16(afr[m], bfr[n], acc[m][n], 0, 0, 0);
        }
    }

    float* Gh = G + ((long)hn << 21);
    #pragma unroll
    for (int m = 0; m < 4; ++m) {
        const long rb = g0 + (wr << 6) + (m << 4) + (og << 2);
        #pragma unroll
        for (int n = 0; n < 4; ++n) {
            const int col = c0 + (wc2 << 6) + (n << 4) + lr;
            #pragma unroll
            for (int j = 0; j < 4; ++j)
                Gh[(rb + j) * 512 + col] = acc[m][n][j];
        }
    }
}

// ---------------------------------------------------------------------------
// gemm2: out = B0 @ Wout^T + p.G. COUNTED-VMCNT 4-BUFFER, DEPTH-3 PIPELINE:
// tiles kt..kt+2 in flight (12 loads); per step wait "vmcnt(8) lgkmcnt(0)"
// (tile kt landed, 8 newer loads stay in flight), barrier, stage kt+3,
// compute kt. Issue->wait gap = 3 compute phases (~600cy) — covers L3
// latency that R14's depth-2 (~400cy) did not. Buffer safety: STAGE(kt+3)
// overwrites buf[(kt-1)&3]; its readers (compute kt-1) drained their
// ds_reads via lgkmcnt(0) before passing barrier(kt).
// ---------------------------------------------------------------------------
__global__ __launch_bounds__(256) void gemm2(
    const unsigned short* __restrict__ A2, const unsigned short* __restrict__ Wre,
    const float* __restrict__ G, const float* __restrict__ p_buf,
    float* __restrict__ out)
{
    __shared__ alignas(16) unsigned short Bl[4][4096];   // 4 x 8 KB
    __shared__ alignas(16) unsigned short Al[4][4096];   // 4 x 8 KB
    __shared__ float pS[512];
    const int tid = threadIdx.x;
    const int l = tid & 63, wid = tid >> 6;
    const int og = l >> 4, lr = l & 15;
    const int wr = wid >> 1, wc2 = wid & 1;
    XCD_DECODE(mt, ct)
    const long t0 = (long)mt * 128;
    const int c0 = ct << 7;

    pS[tid]       = p_buf[t0 * 4 + tid];
    pS[tid + 256] = p_buf[t0 * 4 + 256 + tid];
    __syncthreads();   // drains everything; pipeline starts with vmcnt=0

    const char* gBbase = (const char*)Wre + ((long)(ct * 16) << 13);
    const char* gAbase = (const char*)A2  + ((long)(mt * 16) << 13);
    const int src_off = (wid << 10) + (l << 4);
    const int dst_off = (wid << 10);              // wave-uniform LDS base

#define STAGE2(kt, buf) do {                                               \
        const char* gB_ = gBbase + ((long)(kt) << 13);                     \
        const char* gA_ = gAbase + ((long)(kt) << 13);                     \
        gload_lds16(gB_ + src_off,        (char*)Bl[buf] + dst_off);       \
        gload_lds16(gB_ + 4096 + src_off, (char*)Bl[buf] + 4096 + dst_off);\
        gload_lds16(gA_ + src_off,        (char*)Al[buf] + dst_off);       \
        gload_lds16(gA_ + 4096 + src_off, (char*)Al[buf] + 4096 + dst_off);\
    } while (0)

    f32x4 acc[4][4];
    #pragma unroll
    for (int m = 0; m < 4; ++m)
        #pragma unroll
        for (int n = 0; n < 4; ++n) acc[m][n] = (f32x4)(0.f);

    // prologue: tiles 0,1,2 in flight (12 loads)
    STAGE2(0, 0);
    STAGE2(1, 1);
    STAGE2(2, 2);

    #pragma unroll
    for (int kt = 0; kt < 16; ++kt) {
        // tile kt landed (own oldest 4 loads done); own ds_reads sampled.
        if (kt < 14)      asm volatile("s_waitcnt vmcnt(8) lgkmcnt(0)" ::: "memory");
        else if (kt < 15) asm volatile("s_waitcnt vmcnt(4) lgkmcnt(0)" ::: "memory");
        else              asm volatile("s_waitcnt vmcnt(0) lgkmcnt(0)" ::: "memory");
        __builtin_amdgcn_s_barrier();
        asm volatile("" ::: "memory");
        if (kt < 13) STAGE2(kt + 3, (kt + 3) & 3);

        const char* AlS = (const char*)Al[kt & 3];
        const char* BlS = (const char*)Bl[kt & 3];
        bf16x8 afr[4], bfr[4];
        #pragma unroll
        for (int m = 0; m < 4; ++m)
            afr[m] = *(const bf16x8*)(AlS + BOFF(og, (wr << 6) + (m << 4) + lr));
        #pragma unroll
        for (int n = 0; n < 4; ++n)
            bfr[n] = *(const bf16x8*)(BlS + BOFF(og, (wc2 << 6) + (n << 4) + lr));
        #pragma unroll
        for (int m = 0; m < 4; ++m)
            #pragma unroll
            for (int n = 0; n < 4; ++n)
                acc[m][n] = __builtin_amdgcn_mfma_f32_16x16x32_bf16(afr[m], bfr[n], acc[m][n], 0, 0, 0);
    }
#undef STAGE2

    #pragma unroll
    for (int m = 0; m < 4; ++m) {
        const long gcm = (t0 >> 4) + (wr << 2) + m;
        #pragma unroll
        for (int n = 0; n < 4; ++n) {
            const int col = c0 + (wc2 << 6) + (n << 4) + lr;
            const float g0v = G[gcm * 512 + col];
            const float g1v = G[(1L << 21) + gcm * 512 + col];
            const float g2v = G[(2L << 21) + gcm * 512 + col];
            const float g3v = G[(3L << 21) + gcm * 512 + col];
            #pragma unroll
            for (int j = 0; j < 4; ++j) {
                const int rl = (wr << 6) + (m << 4) + (og << 2) + j;
                const float add = pS[rl*4]*g0v + pS[rl*4+1]*g1v + pS[rl*4+2]*g2v + pS[rl*4+3]*g3v;
                out[(t0 + rl) * 512 + col] = acc[m][n][j] + add;
            }
        }
    }
}

extern "C" void kernel_launch(void* const* d_in, const int* in_sizes, int n_in,
                              void* d_out, int out_size, void* d_ws, size_t ws_size,
                              hipStream_t stream) {
    const float* x       = (const float*)d_in[0];
    const float* h       = (const float*)d_in[1];
    const float* Win     = (const float*)d_in[2];
    const float* gamma   = (const float*)d_in[3];
    const float* beta    = (const float*)d_in[4];
    const float* Wg      = (const float*)d_in[5];
    const float* bg      = (const float*)d_in[6];
    const float* eig_raw = (const float*)d_in[7];
    const float* Wout    = (const float*)d_in[8];

    float* out    = (float*)d_out;
    float* h_last = out + (long)NTOK * DH_;
    unsigned short* xpb = (unsigned short*)d_out;   // bf16 xp, dead before gemm2 writes

    float* ws     = (float*)d_ws;
    float* p_buf  = ws;                            //  262144 f
    float* h0_buf = ws + 262144;                   // 2097152 f
    float* B15    = ws + 2359296;                  // 2097152 f
    float* G      = ws + 4456448;                  // 8388608 f
    unsigned short* WreA = (unsigned short*)(ws + 12845056);  // 262144 us
    unsigned short* WreB = WreA + 262144;                     // 262144 us
    unsigned short* A2   = (unsigned short*)(ws + 13107200);  // 33554432 us

    // scan scratch aliases G (G is produced by kG AFTER the scan finishes)
    float* Pg  = G;                 // 131072 f
    float* Qg  = G + 131072;        // 131072 f
    float* h0g = G + 262144;        // 131072 f

    k0_convert<<<1024, 256, 0, stream>>>(Win, Wout, WreA, WreB);
    gemm1<<<2048, 256, 0, stream>>>(x, WreA, xpb);
    k_lnA<<<NTOK/16, 256, 0, stream>>>(xpb, gamma, beta, Wg, bg, eig_raw,
                                       A2, B15, p_buf);
    k3a_compose<<<512, 256, 0, stream>>>(p_buf, B15, Pg, Qg);
    k3b_scan<<<16, 256, 0, stream>>>(Pg, Qg, h, h0g, h_last);
    k3c_expand<<<512, 256, 0, stream>>>(p_buf, B15, h0g, h0_buf);
    kG<<<512, 256, 0, stream>>>(h0_buf, WreB, G);
    gemm2<<<2048, 256, 0, stream>>>(A2, WreB, G, p_buf, out);
}